// Round 6
// baseline (329.395 us; speedup 1.0000x reference)
//
#include <hip/hip_runtime.h>
#include <hip/hip_bf16.h>
#include <stdint.h>

typedef short bf16x8 __attribute__((ext_vector_type(8)));
typedef float f32x4 __attribute__((ext_vector_type(4)));

__device__ __forceinline__ unsigned short f2bf(float x) {
  uint32_t u = __builtin_bit_cast(uint32_t, x);
  u += 0x7FFFu + ((u >> 16) & 1u);
  return (unsigned short)(u >> 16);
}
__device__ __forceinline__ float bf2f(unsigned short u) {
  uint32_t v = ((uint32_t)u) << 16;
  return __builtin_bit_cast(float, v);
}

__device__ __forceinline__ void gl2lds16(const void* g, void* l) {
  __builtin_amdgcn_global_load_lds(
      (const __attribute__((address_space(1))) unsigned int*)g,
      (__attribute__((address_space(3))) unsigned int*)l, 16, 0, 0);
}

__global__ __launch_bounds__(256) void cast_f32_bf16_k(
    const float* __restrict__ s, unsigned short* __restrict__ d, long n) {
  long i = ((long)blockIdx.x * 256 + threadIdx.x) * 8;
  if (i >= n) return;
  float4 a = *(const float4*)(s + i);
  float4 b = *(const float4*)(s + i + 4);
  bf16x8 o;
  o[0] = (short)f2bf(a.x); o[1] = (short)f2bf(a.y);
  o[2] = (short)f2bf(a.z); o[3] = (short)f2bf(a.w);
  o[4] = (short)f2bf(b.x); o[5] = (short)f2bf(b.y);
  o[6] = (short)f2bf(b.z); o[7] = (short)f2bf(b.w);
  *(bf16x8*)(d + i) = o;
}

__global__ __launch_bounds__(256) void cast4_f32_bf16_k(
    const float* __restrict__ s0, const float* __restrict__ s1,
    const float* __restrict__ s2, const float* __restrict__ s3,
    unsigned short* __restrict__ d, long n) {
  const float* s = blockIdx.z == 0 ? s0 : blockIdx.z == 1 ? s1 : blockIdx.z == 2 ? s2 : s3;
  long i = ((long)blockIdx.x * 256 + threadIdx.x) * 8;
  if (i >= n) return;
  float4 a = *(const float4*)(s + i);
  float4 b = *(const float4*)(s + i + 4);
  bf16x8 o;
  o[0] = (short)f2bf(a.x); o[1] = (short)f2bf(a.y);
  o[2] = (short)f2bf(a.z); o[3] = (short)f2bf(a.w);
  o[4] = (short)f2bf(b.x); o[5] = (short)f2bf(b.y);
  o[6] = (short)f2bf(b.z); o[7] = (short)f2bf(b.w);
  *(bf16x8*)(d + blockIdx.z * n + i) = o;
}

// ============================================================================
// 256x256 m201-style 8-phase GEMM: C = alpha * A[M,K] @ B[N,K]^T  (bf16 in)
// 8 waves (2M x 4N), BK=64, 2 K-tiles/iter. LDS = 8 half-tile regions of 16KB
// ([dbuf][op][half], half = 128 rows x 64 cols), 128KB. XOR swizzle
// phys_col = col ^ ((row&7)<<4), conflict-free (R3-verified: 0 conflicts).
// Per phase (d=tile-within-iter, mq=M-quad): {ds_read A-quad (4 b128; +B 8 at
// mq0), stage one half-tile (2 gl2lds), [lgkm(8) at mq0], barrier, lgkm(0),
// sched_barrier, setprio(1), 16 MFMA, setprio(0), [vmcnt gate at mq3],
// barrier}. Stage schedule/gates (hand-verified FIFO):
//   (0,0): A(u+1)x2   (0,1): B(u+2)h0  (0,2): B(u+2)h1
//   (1,0): A(u+2)x2   (1,1): B(u+3)h0  (1,2): B(u+3)h1     [u = 2*iter]
//   gate end (0,3): vmcnt(4) (last iter: 0) -> A(u+1) landed, 4 in flight
//   gate end (1,3): vmcnt(4) if more iters -> A(u+2)+older landed
// Loads waited on are ~4 phases old; never drain to 0 mid-loop.
// FUSEQKV: B = [Wq;Wk;Wv] (N=3072); per-bn routing, V written transposed.
// ============================================================================
template <typename OutT, bool FUSEQKV>
__global__ __launch_bounds__(512, 2) void gemm_bt8(
    const unsigned short* __restrict__ A, const unsigned short* __restrict__ B,
    OutT* __restrict__ C, int M, int N, int K,
    long sA, long sB, long sC, float alpha) {
  extern __shared__ __align__(16) char smem[];
  const int bz = blockIdx.z;
  const int gx = gridDim.x;
  const int nwg = gx * gridDim.y;  // must be %8==0
  const int idx = blockIdx.y * gx + blockIdx.x;
  const int wg = (idx & 7) * (nwg >> 3) + (idx >> 3);
  const int bm = wg / gx, bn = wg % gx;

  const int tid = threadIdx.x, lane = tid & 63, wave = tid >> 6;
  const int wm = wave >> 2, wn = wave & 3;

  const char* Ac = (const char*)(A + (long)bz * sA + (long)bm * 256 * K);
  const char* Bc = (const char*)(B + (long)bz * sB + (long)bn * 256 * K);
  C += (long)bz * sC;
  const long ld = (long)K * 2;

  // staging: region = 128 rows x 128B; thread covers 2 chunks of 16B
  const int sr8 = tid >> 3;                               // row within chunk
  const int scolx = (((tid & 7) ^ ((tid >> 3) & 7)) << 4);  // pre-swizzled col

  auto stageHalf = [&](int t, int op, int h, const char* gbase) {
    char* reg = smem + (((((t & 1) << 1) | op) << 1 | h) << 14);
    const long ktb = (long)t << 7;
#pragma unroll
    for (int c = 0; c < 2; ++c)
      gl2lds16(gbase + (long)(h * 128 + c * 64 + sr8) * ld + ktb + scolx,
               reg + c * 8192 + tid * 16);
  };

  // read addressing
  const char* Areg[2] = { smem + ((0 << 2 | wm) << 14),
                          smem + ((1 << 2 | wm) << 14) };         // [d][op=0][h=wm]
  const char* Breg[2] = { smem + (((0 << 2) | 2 | (wn >> 1)) << 14),
                          smem + (((1 << 2) | 2 | (wn >> 1)) << 14) };
  const int cko[2] = { (((lane >> 4) << 4) ^ ((lane & 7) << 4)),
                       ((64 | ((lane >> 4) << 4)) ^ ((lane & 7) << 4)) };
  const int rowA0 = (lane & 15) * 128;
  const int rowB0 = ((wn & 1) * 64 + (lane & 15)) * 128;

  f32x4 acc[8][4] = {};

  // prologue: B(0), A(0), B(1) = 12 loads; drain to 4 (B(0)+A(0) landed)
  stageHalf(0, 1, 0, Bc); stageHalf(0, 1, 1, Bc);
  stageHalf(0, 0, 0, Ac); stageHalf(0, 0, 1, Ac);
  stageHalf(1, 1, 0, Bc); stageHalf(1, 1, 1, Bc);
  asm volatile("s_waitcnt vmcnt(4)" ::: "memory");
  __builtin_amdgcn_s_barrier();

  const int nt = K >> 6;         // even, >= 4
  const int niter = nt >> 1;
  for (int i = 0; i < niter; ++i) {
    const int u = 2 * i;
    const bool pf = (i + 1 < niter);
#pragma unroll
    for (int d = 0; d < 2; ++d) {
      bf16x8 b[4][2];
#pragma unroll
      for (int mq = 0; mq < 4; ++mq) {
        bf16x8 a[2][2];
        if (mq == 0) {
#pragma unroll
          for (int n = 0; n < 4; ++n)
#pragma unroll
            for (int kh = 0; kh < 2; ++kh)
              b[n][kh] = *(const bf16x8*)(Breg[d] + rowB0 + n * 2048 + cko[kh]);
        }
#pragma unroll
        for (int j = 0; j < 2; ++j)
#pragma unroll
          for (int kh = 0; kh < 2; ++kh)
            a[j][kh] = *(const bf16x8*)(Areg[d] + rowA0 + (mq * 2 + j) * 2048 + cko[kh]);
        // stage schedule
        if (d == 0 && mq == 0) { stageHalf(u + 1, 0, 0, Ac); stageHalf(u + 1, 0, 1, Ac); }
        if (d == 0 && mq == 1 && pf) stageHalf(u + 2, 1, 0, Bc);
        if (d == 0 && mq == 2 && pf) stageHalf(u + 2, 1, 1, Bc);
        if (d == 1 && mq == 0 && pf) { stageHalf(u + 2, 0, 0, Ac); stageHalf(u + 2, 0, 1, Ac); }
        if (d == 1 && mq == 1 && pf) stageHalf(u + 3, 1, 0, Bc);
        if (d == 1 && mq == 2 && pf) stageHalf(u + 3, 1, 1, Bc);
        if (mq == 0) asm volatile("s_waitcnt lgkmcnt(8)" ::: "memory");
        __builtin_amdgcn_s_barrier();
        asm volatile("s_waitcnt lgkmcnt(0)" ::: "memory");
        __builtin_amdgcn_sched_barrier(0);
        __builtin_amdgcn_s_setprio(1);
#pragma unroll
        for (int kh = 0; kh < 2; ++kh)
#pragma unroll
          for (int j = 0; j < 2; ++j)
#pragma unroll
            for (int n = 0; n < 4; ++n)
              acc[mq * 2 + j][n] = __builtin_amdgcn_mfma_f32_16x16x32_bf16(
                  a[j][kh], b[n][kh], acc[mq * 2 + j][n], 0, 0, 0);
        __builtin_amdgcn_s_setprio(0);
        if (d == 0 && mq == 3) {
          if (pf) asm volatile("s_waitcnt vmcnt(4)" ::: "memory");
          else    asm volatile("s_waitcnt vmcnt(0)" ::: "memory");
        }
        if (d == 1 && mq == 3 && pf) asm volatile("s_waitcnt vmcnt(4)" ::: "memory");
        __builtin_amdgcn_s_barrier();
      }
    }
  }

  // epilogue: C/D layout col=lane&15, row=(lane>>4)*4+reg  [m89/m91 verified]
  const long row0 = (long)bm * 256 + wm * 128 + (lane >> 4) * 4;
  const int col0 = bn * 256 + wn * 64 + (lane & 15);
  if constexpr (FUSEQKV) {
    const int tensor = bn >> 2;  // gx==12: 0=Q,1=K,2=V
    unsigned short* dst = (unsigned short*)C + ((long)tensor << 24);
    const int colb0 = col0 - (tensor << 10);
#pragma unroll
    for (int m = 0; m < 8; ++m) {
#pragma unroll
      for (int n = 0; n < 4; ++n) {
        if (tensor < 2) {
#pragma unroll
          for (int r = 0; r < 4; ++r)
            dst[(row0 + m * 16 + r) * 1024 + colb0 + n * 16] = f2bf(acc[m][n][r]);
        } else {
          long row = row0 + m * 16;
          long base = ((row >> 11) << 21) + ((long)(colb0 + n * 16) << 11) + (row & 2047);
          ushort4 st;
          st.x = f2bf(acc[m][n][0]); st.y = f2bf(acc[m][n][1]);
          st.z = f2bf(acc[m][n][2]); st.w = f2bf(acc[m][n][3]);
          *(ushort4*)(dst + base) = st;
        }
      }
    }
  } else {
#pragma unroll
    for (int m = 0; m < 8; ++m) {
#pragma unroll
      for (int n = 0; n < 4; ++n) {
#pragma unroll
        for (int r = 0; r < 4; ++r) {
          long row = row0 + m * 16 + r;
          int col = col0 + n * 16;
          float v = acc[m][n][r] * alpha;
          if constexpr (sizeof(OutT) == 2)
            C[row * (long)N + col] = (OutT)f2bf(v);
          else
            C[row * (long)N + col] = v;
        }
      }
    }
  }
}

// in-place row softmax on bf16 rows of length C (C == 2048, 256 thr * 8)
__global__ __launch_bounds__(256) void softmax_inplace(unsigned short* __restrict__ s, int C) {
  __shared__ float red[8];
  long row = blockIdx.x;
  unsigned short* p = s + row * (long)C;
  int tid = threadIdx.x, lane = tid & 63, w = tid >> 6;
  bf16x8 raw = *(const bf16x8*)(p + tid * 8);
  float v[8];
  float mx = -3.4e38f;
#pragma unroll
  for (int j = 0; j < 8; ++j) { v[j] = bf2f((unsigned short)raw[j]); mx = fmaxf(mx, v[j]); }
#pragma unroll
  for (int o = 32; o > 0; o >>= 1) mx = fmaxf(mx, __shfl_xor(mx, o));
  if (lane == 0) red[w] = mx;
  __syncthreads();
  mx = fmaxf(fmaxf(red[0], red[1]), fmaxf(red[2], red[3]));
  float sum = 0.f;
#pragma unroll
  for (int j = 0; j < 8; ++j) { v[j] = __expf(v[j] - mx); sum += v[j]; }
#pragma unroll
  for (int o = 32; o > 0; o >>= 1) sum += __shfl_xor(sum, o);
  if (lane == 0) red[4 + w] = sum;
  __syncthreads();
  float inv = 1.f / (red[4] + red[5] + red[6] + red[7]);
  bf16x8 o8;
#pragma unroll
  for (int j = 0; j < 8; ++j) o8[j] = (short)f2bf(v[j] * inv);
  *(bf16x8*)(p + tid * 8) = o8;
}

extern "C" void kernel_launch(void* const* d_in, const int* in_sizes, int n_in,
                              void* d_out, int out_size, void* d_ws, size_t ws_size,
                              hipStream_t stream) {
  (void)in_sizes; (void)n_in; (void)out_size; (void)ws_size;
  const float* x  = (const float*)d_in[0];
  const float* Wq = (const float*)d_in[1];
  const float* Wk = (const float*)d_in[2];
  const float* Wv = (const float*)d_in[3];
  const float* Wo = (const float*)d_in[4];
  const int B = 8, S = 2048, D = 1024;
  const long MB = 1 << 20;
  char* w = (char*)d_ws;
  unsigned short* Wqb = (unsigned short*)(w + 0 * MB);   // Wq,Wk,Wv contiguous (6MB)
  unsigned short* Wob = (unsigned short*)(w + 6 * MB);
  unsigned short* xb  = (unsigned short*)(w + 8 * MB);
  unsigned short* qb  = (unsigned short*)(w + 40 * MB);
  unsigned short* kb  = (unsigned short*)(w + 72 * MB);  // qb+16M elems
  unsigned short* vt  = (unsigned short*)(w + 104 * MB); // qb+32M elems (V^T [B][D][S])
  unsigned short* wb  = xb;  // x dead after projections
  unsigned short* attn = (unsigned short*)d_out;
  float* out = (float*)d_out;

  long nx = (long)B * S * D;
  long nw = (long)D * D;

  const int LDSB = 131072;
  hipFuncSetAttribute((const void*)gemm_bt8<unsigned short, true>,
                      hipFuncAttributeMaxDynamicSharedMemorySize, LDSB);
  hipFuncSetAttribute((const void*)gemm_bt8<unsigned short, false>,
                      hipFuncAttributeMaxDynamicSharedMemorySize, LDSB);
  hipFuncSetAttribute((const void*)gemm_bt8<float, false>,
                      hipFuncAttributeMaxDynamicSharedMemorySize, LDSB);

  cast_f32_bf16_k<<<(int)(nx / 2048), 256, 0, stream>>>(x, xb, nx);
  dim3 gW((int)(nw / 2048), 1, 4);
  cast4_f32_bf16_k<<<gW, 256, 0, stream>>>(Wq, Wk, Wv, Wo, Wqb, nw);

  // fused QKV projection: [16384,1024] @ [3072,1024]^T; per-bn routing Q/K/V^T
  dim3 gF(3072 / 256, (B * S) / 256, 1);
  gemm_bt8<unsigned short, true><<<gF, 512, LDSB, stream>>>(
      xb, Wqb, qb, B * S, 3072, D, 0, 0, 0, 1.f);

  // scores = (1/32) q @ k^T -> bf16 in d_out
  dim3 gS(S / 256, S / 256, B);
  gemm_bt8<unsigned short, false><<<gS, 512, LDSB, stream>>>(qb, kb, attn, S, S, D,
      (long)S * D, (long)S * D, (long)S * S, 0.03125f);

  softmax_inplace<<<B * S, 256, 0, stream>>>(attn, S);

  // weighted = attn @ v  (vt is [D][S]) : per batch M=2048, N=1024, K=2048
  dim3 gPV(D / 256, S / 256, B);
  gemm_bt8<unsigned short, false><<<gPV, 512, LDSB, stream>>>(attn, vt, wb, S, D, S,
      (long)S * S, (long)D * S, (long)S * D, 1.f);

  // out = weighted @ Wo^T (fp32): M=16384, N=1024, K=1024
  dim3 gP(D / 256, (B * S) / 256, 1);
  gemm_bt8<float, false><<<gP, 512, LDSB, stream>>>(wb, Wob, out, B * S, D, D, 0, 0, 0, 1.f);
}